// Round 1
// baseline (1194.067 us; speedup 1.0000x reference)
//
#include <hip/hip_runtime.h>

typedef unsigned short u16;
typedef unsigned int u32;
typedef __attribute__((ext_vector_type(8))) __bf16 bf16x8;
typedef __attribute__((ext_vector_type(4))) float f32x4;
typedef __attribute__((ext_vector_type(4))) u32 u32x4;
typedef __attribute__((ext_vector_type(8))) u16 u16x8;

#define S_LEN 2048
#define DM 3072
#define NH 24
#define NKV 8

__device__ __forceinline__ u16 f2b(float f) {
  u32 u = __builtin_bit_cast(u32, f);
  u = u + 0x7FFFu + ((u >> 16) & 1u);
  return (u16)(u >> 16);
}
__device__ __forceinline__ float b2f(u16 h) {
  u32 u = ((u32)h) << 16;
  return __builtin_bit_cast(float, u);
}
__device__ __forceinline__ f32x4 mfma16(bf16x8 a, bf16x8 b, f32x4 c) {
  return __builtin_amdgcn_mfma_f32_16x16x32_bf16(a, b, c, 0, 0, 0);
}
__device__ __forceinline__ void gload16(const u16* g, u16* l) {
  __builtin_amdgcn_global_load_lds((const __attribute__((address_space(1))) void*)g,
                                   (__attribute__((address_space(3))) void*)l, 16, 0, 0);
}

// ---------------- f32 -> bf16 conversion ----------------
__global__ __launch_bounds__(256) void cvt_kernel(const float* __restrict__ s,
                                                  u16* __restrict__ d, int n8) {
  int i = blockIdx.x * 256 + threadIdx.x;
  if (i >= n8) return;
  const f32x4* p = (const f32x4*)(s + (size_t)i * 8);
  f32x4 a = p[0], b = p[1];
  u16x8 o;
#pragma unroll
  for (int j = 0; j < 4; ++j) { o[j] = f2b(a[j]); o[j + 4] = f2b(b[j]); }
  *(u16x8*)(d + (size_t)i * 8) = o;
}

// ---------------- GEMM: C[m,n] = sum_k A[m,k] * B[n,k] (both bf16 row-major over K) ----------------
// 128x128 tile, BK=32, 4 waves (2x2 of 64x64), m97 structure.
__device__ __forceinline__ void gemm_body(const u16* __restrict__ A, const u16* __restrict__ B,
                                          void* __restrict__ Cv, int N, int K,
                                          int m0, int n0, int outf32) {
  __shared__ __align__(16) u16 sA[128 * 32];
  __shared__ __align__(16) u16 sB[128 * 32];
  const int tid = threadIdx.x;
  const int w = tid >> 6, lane = tid & 63;
  const int l15 = lane & 15, g = lane >> 4;
  const int wr = w >> 1, wc = w & 1;
  f32x4 acc[4][4];
#pragma unroll
  for (int i = 0; i < 4; ++i)
#pragma unroll
    for (int j = 0; j < 4; ++j) acc[i][j] = 0.f;

  for (int k0 = 0; k0 < K; k0 += 32) {
    __syncthreads();
#pragma unroll
    for (int t = 0; t < 2; ++t) {
      int jb = w * 128 + t * 64;      // wave-uniform chunk base
      int jc = jb + lane;             // this lane's 16B chunk
      int row = jc >> 2, c8 = (jc & 3) << 3;
      gload16(A + (size_t)(m0 + row) * K + k0 + c8, sA + jb * 8);
      gload16(B + (size_t)(n0 + row) * K + k0 + c8, sB + jb * 8);
    }
    __syncthreads();
    bf16x8 af[4], bfr[4];
#pragma unroll
    for (int i = 0; i < 4; ++i) {
      af[i]  = *(const bf16x8*)(sA + (wr * 64 + i * 16 + l15) * 32 + g * 8);
      bfr[i] = *(const bf16x8*)(sB + (wc * 64 + i * 16 + l15) * 32 + g * 8);
    }
#pragma unroll
    for (int i = 0; i < 4; ++i)
#pragma unroll
      for (int j = 0; j < 4; ++j)
        acc[i][j] = mfma16(af[i], bfr[j], acc[i][j]);
  }
  // C/D layout: col = lane&15, row = (lane>>4)*4 + reg
#pragma unroll
  for (int i = 0; i < 4; ++i)
#pragma unroll
    for (int j = 0; j < 4; ++j)
#pragma unroll
      for (int r = 0; r < 4; ++r) {
        size_t off = (size_t)(m0 + wr * 64 + i * 16 + g * 4 + r) * N
                   + (size_t)(n0 + wc * 64 + j * 16 + l15);
        if (outf32) ((float*)Cv)[off] = acc[i][j][r];
        else        ((u16*)Cv)[off]   = f2b(acc[i][j][r]);
      }
}

__global__ __launch_bounds__(256) void gemm_bf16out(const u16* __restrict__ A, const u16* __restrict__ B,
                                                    u16* __restrict__ C, int N, int K) {
  gemm_body(A, B, C, N, K, blockIdx.y * 128, blockIdx.x * 128, 0);
}
__global__ __launch_bounds__(256) void gemm_f32out(const u16* __restrict__ A, const u16* __restrict__ B,
                                                   float* __restrict__ C, int N, int K) {
  gemm_body(A, B, C, N, K, blockIdx.y * 128, blockIdx.x * 128, 1);
}
// fused K and V projections: grid.x = 16, first 8 -> K, last 8 -> V
__global__ __launch_bounds__(256) void gemm_kv(const u16* __restrict__ A,
                                               const u16* __restrict__ Bk, const u16* __restrict__ Bv,
                                               u16* __restrict__ Ck, u16* __restrict__ Cv,
                                               int N, int K) {
  bool isv = blockIdx.x >= 8;
  gemm_body(A, isv ? Bv : Bk, isv ? Cv : Ck, N, K, blockIdx.y * 128, (blockIdx.x & 7) * 128, 0);
}

// ---------------- RoPE (in place, bf16) ----------------
__global__ __launch_bounds__(256) void rope_kernel(u16* __restrict__ t, const float* __restrict__ fc,
                                                   const float* __restrict__ fs, int nheads, int total) {
  int idx = blockIdx.x * 256 + threadIdx.x;
  if (idx >= total) return;
  int c = idx & 7;
  int tmp = idx >> 3;
  int h = tmp % nheads;
  int row = tmp / nheads;         // b*S + s
  int s = row & (S_LEN - 1);
  int d0 = c << 3;
  u16* base = t + (size_t)row * (nheads * 128) + h * 128;
  u16x8 lo = *(const u16x8*)(base + d0);
  u16x8 hi = *(const u16x8*)(base + 64 + d0);
  const float* cp = fc + s * 64 + d0;
  const float* sp = fs + s * 64 + d0;
  u16x8 olo, ohi;
#pragma unroll
  for (int j = 0; j < 8; ++j) {
    float cv = cp[j], sn = sp[j];
    float a = b2f(lo[j]), b = b2f(hi[j]);
    olo[j] = f2b(a * cv - b * sn);
    ohi[j] = f2b(b * cv + a * sn);
  }
  *(u16x8*)(base + d0) = olo;
  *(u16x8*)(base + 64 + d0) = ohi;
}

// ---------------- causal GQA flash attention ----------------
// grid: (S/64, H, B); block 256 (4 waves x 16 q-rows). Swapped QK^T: scores kept
// transposed so each lane owns one q-row (q = lane&15) for softmax state.
__global__ __launch_bounds__(256) void attn_kernel(const u16* __restrict__ xq,
                                                   const u16* __restrict__ xk,
                                                   const u16* __restrict__ xv,
                                                   u16* __restrict__ o) {
  __shared__ __align__(16) u16 smem[21504];     // 43 KB
  u16* sK = smem;                               // [64][128] bf16, XOR-swizzled
  u16* sV = smem + 8192;                        // Vt [128][72] bf16 (transposed, padded)
  const int tid = threadIdx.x;
  const int w = tid >> 6, lane = tid & 63;
  const int l15 = lane & 15, g = lane >> 4;
  u16* sP = smem + 17408 + w * 1024;            // per-wave P [16][64] bf16, XOR-swizzled
  const int b = blockIdx.z, h = blockIdx.y, qb = blockIdx.x;
  const int kvh = h / 3;                        // N_REP = 3 (repeat_interleave)
  const int q0 = qb * 64;
  const int qrow = q0 + w * 16 + l15;           // this lane's global q
  const u16* qptr = xq + (size_t)(b * S_LEN + qrow) * DM + h * 128;
  bf16x8 qf[4];
#pragma unroll
  for (int dc = 0; dc < 4; ++dc)
    qf[dc] = *(const bf16x8*)(qptr + dc * 32 + g * 8);

  f32x4 accO[8];                                // O^T: d = dt*16 + g*4 + r, col q = l15
#pragma unroll
  for (int i = 0; i < 8; ++i) accO[i] = 0.f;
  float m = -1e30f, lsum = 0.f;
  const int nt = qb + 1;
  const float sc = 0.08838834764831845f;        // 1/sqrt(128)

  for (int t = 0; t < nt; ++t) {
    const int k0 = t * 64;
    __syncthreads();                            // prior-tile LDS reads done
    // stage K tile [64][128] with row-XOR swizzle
#pragma unroll
    for (int p = 0; p < 4; ++p) {
      int c = p * 256 + tid;
      int row = c >> 4, c8 = (c & 15) << 3;
      u32x4 v = *(const u32x4*)(xk + (size_t)(b * S_LEN + k0 + row) * 1024 + kvh * 128 + c8);
      *(u32x4*)(sK + ((row * 128 + c8) ^ ((row & 7) << 3))) = v;
    }
    // stage V transposed: Vt[d][k], padded stride 72, diagonal-rotated scalar writes
#pragma unroll
    for (int p = 0; p < 4; ++p) {
      int c = p * 256 + tid;
      int k = c >> 4, d0 = (c & 15) << 3;
      u16x8 v = *(const u16x8*)(xv + (size_t)(b * S_LEN + k0 + k) * 1024 + kvh * 128 + d0);
      int rot = c & 7;
#pragma unroll
      for (int i = 0; i < 8; ++i) {
        int j = (i + rot) & 7;
        sV[(d0 + j) * 72 + k] = v[j];
      }
    }
    __syncthreads();
    // S^T[k][q] = sum_d K[k][d] Q[q][d]
    f32x4 st[4];
#pragma unroll
    for (int kt = 0; kt < 4; ++kt) {
      f32x4 a = 0.f;
#pragma unroll
      for (int dc = 0; dc < 4; ++dc) {
        int row = kt * 16 + l15;
        bf16x8 kf = *(const bf16x8*)(sK + ((row * 128 + dc * 32 + g * 8) ^ ((row & 7) << 3)));
        a = mfma16(kf, qf[dc], a);
      }
      st[kt] = a;
    }
    // scale + causal mask (only diagonal tile) + online softmax
    float sv[4][4];
    float pmax = -1e30f;
#pragma unroll
    for (int kt = 0; kt < 4; ++kt)
#pragma unroll
      for (int r = 0; r < 4; ++r) {
        float x = st[kt][r] * sc;
        if (t == nt - 1) {
          int kk = k0 + kt * 16 + g * 4 + r;
          if (kk > qrow) x = -1e30f;
        }
        sv[kt][r] = x;
        pmax = fmaxf(pmax, x);
      }
    pmax = fmaxf(pmax, __shfl_xor(pmax, 16));
    pmax = fmaxf(pmax, __shfl_xor(pmax, 32));
    float mnew = fmaxf(m, pmax);
    float corr = __expf(m - mnew);
    float ps = 0.f;
#pragma unroll
    for (int kt = 0; kt < 4; ++kt)
#pragma unroll
      for (int r = 0; r < 4; ++r) {
        float p = __expf(sv[kt][r] - mnew);
        ps += p;
        int kk = kt * 16 + g * 4 + r;
        sP[(l15 * 64 + kk) ^ ((l15 & 7) << 3)] = f2b(p);
      }
    ps += __shfl_xor(ps, 16);
    ps += __shfl_xor(ps, 32);
    lsum = lsum * corr + ps;
    m = mnew;
#pragma unroll
    for (int i = 0; i < 8; ++i) accO[i] *= corr;
    __syncthreads();                            // P visible (wave-local + block)
    // PV: out^T[d][q] += Vt[d][k] * P[q][k]
    bf16x8 pf[2];
#pragma unroll
    for (int ck = 0; ck < 2; ++ck)
      pf[ck] = *(const bf16x8*)(sP + ((l15 * 64 + ck * 32 + g * 8) ^ ((l15 & 7) << 3)));
#pragma unroll
    for (int dt = 0; dt < 8; ++dt)
#pragma unroll
      for (int ck = 0; ck < 2; ++ck) {
        bf16x8 vf = *(const bf16x8*)(sV + (dt * 16 + l15) * 72 + ck * 32 + g * 8);
        accO[dt] = mfma16(vf, pf[ck], accO[dt]);
      }
  }
  // epilogue: normalize, transpose via LDS (reuse sK region), coalesced bf16 writes
  __syncthreads();
  u16* sO = smem + w * 2048;                    // per-wave [16][128] bf16, XOR-swizzled
  float invl = 1.0f / lsum;
#pragma unroll
  for (int dt = 0; dt < 8; ++dt)
#pragma unroll
    for (int r = 0; r < 4; ++r) {
      int d = dt * 16 + g * 4 + r;
      sO[(l15 * 128 + d) ^ ((l15 & 7) << 3)] = f2b(accO[dt][r] * invl);
    }
  __syncthreads();
#pragma unroll
  for (int p = 0; p < 4; ++p) {
    int idx = p * 64 + lane;
    int q = idx >> 4, d0 = (idx & 15) << 3;
    u32x4 v = *(const u32x4*)(sO + ((q * 128 + d0) ^ ((q & 7) << 3)));
    *(u32x4*)(o + (size_t)(b * S_LEN + q0 + w * 16 + q) * DM + h * 128 + d0) = v;
  }
}

// ---------------- launch ----------------
extern "C" void kernel_launch(void* const* d_in, const int* in_sizes, int n_in,
                              void* d_out, int out_size, void* d_ws, size_t ws_size,
                              hipStream_t stream) {
  const float* x  = (const float*)d_in[0];
  const float* fc = (const float*)d_in[1];
  const float* fs = (const float*)d_in[2];
  const float* wq = (const float*)d_in[4];
  const float* wk = (const float*)d_in[5];
  const float* wv = (const float*)d_in[6];
  const float* wo = (const float*)d_in[7];
  float* out = (float*)d_out;
  char* ws = (char*)d_ws;

  // workspace layout (bytes); total 98,566,144 (~94 MB)
  u16* xb  = (u16*)(ws);                 // x bf16      25,165,824
  u16* wqb = (u16*)(ws + 25165824);      // wq bf16     18,874,368
  u16* att = (u16*)(ws + 25165824);      // attn out    25,165,824 (aliases wq/wk after they die)
  u16* wkb = (u16*)(ws + 44040192);      // wk bf16      6,291,456
  u16* wvb = (u16*)(ws + 50331648);      // wv bf16      6,291,456
  u16* xqb = (u16*)(ws + 56623104);      // xq bf16     25,165,824
  u16* xkb = (u16*)(ws + 81788928);      // xk bf16      8,388,608
  u16* xvb = (u16*)(ws + 90177536);      // xv bf16      8,388,608
  u16* wob = (u16*)(ws);                 // wo bf16 (aliases xb after it dies)

  cvt_kernel<<<6144, 256, 0, stream>>>(x,  xb,  1572864);
  cvt_kernel<<<4608, 256, 0, stream>>>(wq, wqb, 1179648);
  cvt_kernel<<<1536, 256, 0, stream>>>(wk, wkb,  393216);
  cvt_kernel<<<1536, 256, 0, stream>>>(wv, wvb,  393216);

  gemm_bf16out<<<dim3(24, 32), 256, 0, stream>>>(xb, wqb, xqb, 3072, 3072);
  gemm_kv<<<dim3(16, 32), 256, 0, stream>>>(xb, wkb, wvb, xkb, xvb, 1024, 3072);

  rope_kernel<<<3072, 256, 0, stream>>>(xqb, fc, fs, NH,  4096 * NH  * 8);
  rope_kernel<<<1024, 256, 0, stream>>>(xkb, fc, fs, NKV, 4096 * NKV * 8);

  attn_kernel<<<dim3(32, NH, 2), 256, 0, stream>>>(xqb, xkb, xvb, att);

  cvt_kernel<<<4608, 256, 0, stream>>>(wo, wob, 1179648);
  gemm_f32out<<<dim3(24, 32), 256, 0, stream>>>(att, wob, out, 3072, 3072);
}

// Round 2
// 535.878 us; speedup vs baseline: 2.2282x; 2.2282x over previous
//
#include <hip/hip_runtime.h>

typedef unsigned short u16;
typedef unsigned int u32;
typedef __attribute__((ext_vector_type(8))) __bf16 bf16x8;
typedef __attribute__((ext_vector_type(4))) float f32x4;
typedef __attribute__((ext_vector_type(4))) u32 u32x4;
typedef __attribute__((ext_vector_type(8))) u16 u16x8;
typedef __attribute__((ext_vector_type(4))) u16 u16x4;

#define S_LEN 2048
#define DM 3072
#define NH 24
#define NKV 8

__device__ __forceinline__ u16 f2b(float f) {
  u32 u = __builtin_bit_cast(u32, f);
  u = u + 0x7FFFu + ((u >> 16) & 1u);
  return (u16)(u >> 16);
}
__device__ __forceinline__ float b2f(u16 h) {
  u32 u = ((u32)h) << 16;
  return __builtin_bit_cast(float, u);
}
__device__ __forceinline__ f32x4 mfma16(bf16x8 a, bf16x8 b, f32x4 c) {
  return __builtin_amdgcn_mfma_f32_16x16x32_bf16(a, b, c, 0, 0, 0);
}
__device__ __forceinline__ void gload16(const u16* g, u16* l) {
  __builtin_amdgcn_global_load_lds((const __attribute__((address_space(1))) void*)g,
                                   (__attribute__((address_space(3))) void*)l, 16, 0, 0);
}

// ---------------- f32 -> bf16 conversion ----------------
__global__ __launch_bounds__(256) void cvt_kernel(const float* __restrict__ s,
                                                  u16* __restrict__ d, int n8) {
  int i = blockIdx.x * 256 + threadIdx.x;
  if (i >= n8) return;
  const f32x4* p = (const f32x4*)(s + (size_t)i * 8);
  f32x4 a = p[0], b = p[1];
  u16x8 o;
#pragma unroll
  for (int j = 0; j < 4; ++j) { o[j] = f2b(a[j]); o[j + 4] = f2b(b[j]); }
  *(u16x8*)(d + (size_t)i * 8) = o;
}

// ---------------- GEMM: C[m,n] = sum_k A[m,k] * B[n,k] ----------------
// 128x128 tile, BK=32, 4 waves (2x2 of 64x64), m97 structure.
// mode 0: bf16 row-major out; mode 1: f32 row-major out; mode 2: bf16 V^T out
// (V^T layout: vT[(b*1024 + n)*2048 + s], where m = b*2048 + s, n in [0,1024)).
__device__ __forceinline__ void gemm_body(const u16* __restrict__ A, const u16* __restrict__ B,
                                          void* __restrict__ Cv, int N, int K,
                                          int m0, int n0, int mode) {
  __shared__ __align__(16) u16 sA[128 * 32];
  __shared__ __align__(16) u16 sB[128 * 32];
  const int tid = threadIdx.x;
  const int w = tid >> 6, lane = tid & 63;
  const int l15 = lane & 15, g = lane >> 4;
  const int wr = w >> 1, wc = w & 1;
  f32x4 acc[4][4];
#pragma unroll
  for (int i = 0; i < 4; ++i)
#pragma unroll
    for (int j = 0; j < 4; ++j) acc[i][j] = 0.f;

  for (int k0 = 0; k0 < K; k0 += 32) {
    __syncthreads();
#pragma unroll
    for (int t = 0; t < 2; ++t) {
      int jb = w * 128 + t * 64;      // wave-uniform chunk base
      int jc = jb + lane;             // this lane's 16B chunk
      int row = jc >> 2, c8 = (jc & 3) << 3;
      gload16(A + (size_t)(m0 + row) * K + k0 + c8, sA + jb * 8);
      gload16(B + (size_t)(n0 + row) * K + k0 + c8, sB + jb * 8);
    }
    __syncthreads();
    bf16x8 af[4], bfr[4];
#pragma unroll
    for (int i = 0; i < 4; ++i) {
      af[i]  = *(const bf16x8*)(sA + (wr * 64 + i * 16 + l15) * 32 + g * 8);
      bfr[i] = *(const bf16x8*)(sB + (wc * 64 + i * 16 + l15) * 32 + g * 8);
    }
#pragma unroll
    for (int i = 0; i < 4; ++i)
#pragma unroll
      for (int j = 0; j < 4; ++j)
        acc[i][j] = mfma16(af[i], bfr[j], acc[i][j]);
  }
  // C/D layout: col = lane&15, row = (lane>>4)*4 + reg
#pragma unroll
  for (int i = 0; i < 4; ++i)
#pragma unroll
    for (int j = 0; j < 4; ++j)
#pragma unroll
      for (int r = 0; r < 4; ++r) {
        int mm = m0 + wr * 64 + i * 16 + g * 4 + r;
        int nn = n0 + wc * 64 + j * 16 + l15;
        if (mode == 1)      ((float*)Cv)[(size_t)mm * N + nn] = acc[i][j][r];
        else if (mode == 0) ((u16*)Cv)[(size_t)mm * N + nn]   = f2b(acc[i][j][r]);
        else                ((u16*)Cv)[(size_t)nn * 2048 + (size_t)(mm >> 11) * 2097152 + (mm & 2047)]
                              = f2b(acc[i][j][r]);
      }
}

__global__ __launch_bounds__(256) void gemm_bf16out(const u16* __restrict__ A, const u16* __restrict__ B,
                                                    u16* __restrict__ C, int N, int K) {
  gemm_body(A, B, C, N, K, blockIdx.y * 128, blockIdx.x * 128, 0);
}
__global__ __launch_bounds__(256) void gemm_f32out(const u16* __restrict__ A, const u16* __restrict__ B,
                                                   float* __restrict__ C, int N, int K) {
  gemm_body(A, B, C, N, K, blockIdx.y * 128, blockIdx.x * 128, 1);
}
// fused K and V projections: grid.x = 16, first 8 -> K (row-major), last 8 -> V (transposed out)
__global__ __launch_bounds__(256) void gemm_kv(const u16* __restrict__ A,
                                               const u16* __restrict__ Bk, const u16* __restrict__ Bv,
                                               u16* __restrict__ Ck, u16* __restrict__ Cv,
                                               int N, int K) {
  bool isv = blockIdx.x >= 8;
  gemm_body(A, isv ? Bv : Bk, isv ? Cv : Ck, N, K, blockIdx.y * 128, (blockIdx.x & 7) * 128,
            isv ? 2 : 0);
}

// ---------------- RoPE (in place, bf16) ----------------
__global__ __launch_bounds__(256) void rope_kernel(u16* __restrict__ t, const float* __restrict__ fc,
                                                   const float* __restrict__ fs, int nheads, int total) {
  int idx = blockIdx.x * 256 + threadIdx.x;
  if (idx >= total) return;
  int c = idx & 7;
  int tmp = idx >> 3;
  int h = tmp % nheads;
  int row = tmp / nheads;         // b*S + s
  int s = row & (S_LEN - 1);
  int d0 = c << 3;
  u16* base = t + (size_t)row * (nheads * 128) + h * 128;
  u16x8 lo = *(const u16x8*)(base + d0);
  u16x8 hi = *(const u16x8*)(base + 64 + d0);
  const float* cp = fc + s * 64 + d0;
  const float* sp = fs + s * 64 + d0;
  u16x8 olo, ohi;
#pragma unroll
  for (int j = 0; j < 8; ++j) {
    float cv = cp[j], sn = sp[j];
    float a = b2f(lo[j]), b = b2f(hi[j]);
    olo[j] = f2b(a * cv - b * sn);
    ohi[j] = f2b(b * cv + a * sn);
  }
  *(u16x8*)(base + d0) = olo;
  *(u16x8*)(base + 64 + d0) = ohi;
}

// ---------------- causal GQA flash attention ----------------
// grid: (S/64, H, B); block 256 (4 waves x 16 q-rows). Swapped QK^T (scores
// transposed, lane owns q-row = lane&15). K and V^T double-buffered in LDS via
// global_load_lds with pre-swizzled sources (XOR swizzle on read). T3 2-phase:
// stage(t+1) issued before compute(t); one __syncthreads per tile.
__global__ __launch_bounds__(256) void attn_kernel(const u16* __restrict__ xq,
                                                   const u16* __restrict__ xk,
                                                   const u16* __restrict__ xvT,
                                                   u16* __restrict__ o) {
  __shared__ __align__(16) u16 smem[36864];     // 72 KB: K dbuf 2x16K, V^T dbuf 2x16K, P 8K
  const int tid = threadIdx.x;
  const int w = tid >> 6, lane = tid & 63;
  const int l15 = lane & 15, g = lane >> 4;
  u16* sP = smem + 32768 + w * 1024;            // per-wave P [16][64] bf16, XOR-swizzled
  const int b = blockIdx.z, h = blockIdx.y;
  const int qb = 31 - blockIdx.x;               // long blocks first (causal tail)
  const int kvh = h / 3;                        // N_REP = 3
  const int q0 = qb * 64;
  const int qrow = q0 + w * 16 + l15;
  const u16* qptr = xq + (size_t)(b * S_LEN + qrow) * DM + h * 128;
  bf16x8 qf[4];
#pragma unroll
  for (int dc = 0; dc < 4; ++dc)
    qf[dc] = *(const bf16x8*)(qptr + dc * 32 + g * 8);

  // stage address precompute: dest linear chunk c holds global chunk c^(row&7) of its row
  const u16* ksrc = xk + (size_t)b * 2097152 + kvh * 128;            // [s][1024] rows
  const u16* vsrc = xvT + (size_t)(b * 1024 + kvh * 128) * 2048;     // [d][2048] rows
  int koff[4], vofs[4], dst[4];
#pragma unroll
  for (int r = 0; r < 4; ++r) {
    int ck = r * 256 + tid;                    // K tile: [64 rows][16 chunks]
    int krow = ck >> 4, kj = (ck & 15) ^ (krow & 7);
    koff[r] = krow * 1024 + kj * 8;
    int cv = r * 256 + tid;                    // V^T tile: [128 rows][8 chunks]
    int vrow = cv >> 3, vj = (cv & 7) ^ (vrow & 7);
    vofs[r] = vrow * 2048 + vj * 8;
    dst[r] = (r * 256 + (tid & 192)) * 8;      // wave-uniform LDS chunk base (elements)
  }

  u16 *sKc = smem, *sKn = smem + 8192;
  u16 *sVc = smem + 16384, *sVn = smem + 24576;

  f32x4 accO[8];
#pragma unroll
  for (int i = 0; i < 8; ++i) accO[i] = 0.f;
  float m = -1e30f, lsum = 0.f;
  const int nt = qb + 1;
  const float sc = 0.08838834764831845f;       // 1/sqrt(128)

  // prologue stage tile 0 into current buffers
#pragma unroll
  for (int r = 0; r < 4; ++r) gload16(ksrc + koff[r], sKc + dst[r]);
#pragma unroll
  for (int r = 0; r < 4; ++r) gload16(vsrc + vofs[r], sVc + dst[r]);
  __syncthreads();

  for (int t = 0; t < nt; ++t) {
    // stage next tile into the other buffers (flies during this tile's compute)
    if (t + 1 < nt) {
      int k0n = (t + 1) * 64;
#pragma unroll
      for (int r = 0; r < 4; ++r) gload16(ksrc + (size_t)k0n * 1024 + koff[r], sKn + dst[r]);
#pragma unroll
      for (int r = 0; r < 4; ++r) gload16(vsrc + k0n + vofs[r], sVn + dst[r]);
    }
    // S^T[k][q] = sum_d K[k][d] Q[q][d]
    f32x4 st[4];
#pragma unroll
    for (int kt = 0; kt < 4; ++kt) {
      f32x4 a = 0.f;
      int row = kt * 16 + l15;
#pragma unroll
      for (int dc = 0; dc < 4; ++dc) {
        bf16x8 kf = *(const bf16x8*)(sKc + row * 128 + ((dc * 32 + g * 8) ^ ((row & 7) << 3)));
        a = mfma16(kf, qf[dc], a);
      }
      st[kt] = a;
    }
    // scale + causal mask (diagonal tile only) + online softmax
    float sv[4][4];
    float pmax = -1e30f;
#pragma unroll
    for (int kt = 0; kt < 4; ++kt)
#pragma unroll
      for (int r = 0; r < 4; ++r) {
        float x = st[kt][r] * sc;
        if (t == nt - 1) {
          int kk = t * 64 + kt * 16 + g * 4 + r;
          if (kk > qrow) x = -1e30f;
        }
        sv[kt][r] = x;
        pmax = fmaxf(pmax, x);
      }
    pmax = fmaxf(pmax, __shfl_xor(pmax, 16));
    pmax = fmaxf(pmax, __shfl_xor(pmax, 32));
    float mnew = fmaxf(m, pmax);
    float corr = __expf(m - mnew);
    float ps = 0.f;
#pragma unroll
    for (int kt = 0; kt < 4; ++kt) {
      u16x4 pk;
#pragma unroll
      for (int r = 0; r < 4; ++r) {
        float p = __expf(sv[kt][r] - mnew);
        ps += p;
        pk[r] = f2b(p);
      }
      // 8B packed P write, swizzled (bits 3-5 of element index)
      *(u16x4*)(sP + ((l15 * 64 + kt * 16 + g * 4) ^ ((l15 & 7) << 3))) = pk;
    }
    ps += __shfl_xor(ps, 16);
    ps += __shfl_xor(ps, 32);
    lsum = lsum * corr + ps;
    m = mnew;
#pragma unroll
    for (int i = 0; i < 8; ++i) accO[i] *= corr;
    // PV: out^T[d][q] += V^T[d][k] * P[q][k]  (P is wave-local; lgkm waits only)
    bf16x8 pf[2];
#pragma unroll
    for (int ck = 0; ck < 2; ++ck)
      pf[ck] = *(const bf16x8*)(sP + ((l15 * 64 + ck * 32 + g * 8) ^ ((l15 & 7) << 3)));
#pragma unroll
    for (int dt = 0; dt < 8; ++dt) {
      int row = dt * 16 + l15;
#pragma unroll
      for (int ck = 0; ck < 2; ++ck) {
        bf16x8 vf = *(const bf16x8*)(sVc + row * 64 + ((ck * 32 + g * 8) ^ ((row & 7) << 3)));
        accO[dt] = mfma16(vf, pf[ck], accO[dt]);
      }
    }
    __syncthreads();                            // drains stage vmcnt + all reads of cur done
    u16* tk = sKc; sKc = sKn; sKn = tk;
    u16* tv = sVc; sVc = sVn; sVn = tv;
  }
  // epilogue: normalize, transpose via LDS, coalesced bf16 writes
  u16* sO = smem + w * 2048;                    // per-wave [16][128] bf16, XOR-swizzled
  float invl = 1.0f / lsum;
#pragma unroll
  for (int dt = 0; dt < 8; ++dt)
#pragma unroll
    for (int r = 0; r < 4; ++r) {
      int d = dt * 16 + g * 4 + r;
      sO[(l15 * 128 + d) ^ ((l15 & 7) << 3)] = f2b(accO[dt][r] * invl);
    }
  __syncthreads();
#pragma unroll
  for (int p = 0; p < 4; ++p) {
    int idx = p * 64 + lane;
    int q = idx >> 4, d0 = (idx & 15) << 3;
    u32x4 v = *(const u32x4*)(sO + ((q * 128 + d0) ^ ((q & 7) << 3)));
    *(u32x4*)(o + (size_t)(b * S_LEN + q0 + w * 16 + q) * DM + h * 128 + d0) = v;
  }
}

// ---------------- launch ----------------
extern "C" void kernel_launch(void* const* d_in, const int* in_sizes, int n_in,
                              void* d_out, int out_size, void* d_ws, size_t ws_size,
                              hipStream_t stream) {
  const float* x  = (const float*)d_in[0];
  const float* fc = (const float*)d_in[1];
  const float* fs = (const float*)d_in[2];
  const float* wq = (const float*)d_in[4];
  const float* wk = (const float*)d_in[5];
  const float* wv = (const float*)d_in[6];
  const float* wo = (const float*)d_in[7];
  float* out = (float*)d_out;
  char* ws = (char*)d_ws;

  // workspace layout (bytes)
  u16* xb  = (u16*)(ws);                 // x bf16      25,165,824
  u16* wqb = (u16*)(ws + 25165824);      // wq bf16     18,874,368
  u16* att = (u16*)(ws + 25165824);      // attn out    25,165,824 (aliases wq/wk after they die)
  u16* wkb = (u16*)(ws + 44040192);      // wk bf16      6,291,456
  u16* wvb = (u16*)(ws + 50331648);      // wv bf16      6,291,456
  u16* xqb = (u16*)(ws + 56623104);      // xq bf16     25,165,824
  u16* xkb = (u16*)(ws + 81788928);      // xk bf16      8,388,608
  u16* xvT = (u16*)(ws + 90177536);      // V^T bf16     8,388,608
  u16* wob = (u16*)(ws);                 // wo bf16 (aliases xb after it dies)

  cvt_kernel<<<6144, 256, 0, stream>>>(x,  xb,  1572864);
  cvt_kernel<<<4608, 256, 0, stream>>>(wq, wqb, 1179648);
  cvt_kernel<<<1536, 256, 0, stream>>>(wk, wkb,  393216);
  cvt_kernel<<<1536, 256, 0, stream>>>(wv, wvb,  393216);

  gemm_bf16out<<<dim3(24, 32), 256, 0, stream>>>(xb, wqb, xqb, 3072, 3072);
  gemm_kv<<<dim3(16, 32), 256, 0, stream>>>(xb, wkb, wvb, xkb, xvT, 1024, 3072);

  rope_kernel<<<3072, 256, 0, stream>>>(xqb, fc, fs, NH,  4096 * NH  * 8);
  rope_kernel<<<1024, 256, 0, stream>>>(xkb, fc, fs, NKV, 4096 * NKV * 8);

  attn_kernel<<<dim3(32, NH, 2), 256, 0, stream>>>(xqb, xkb, xvT, att);

  cvt_kernel<<<4608, 256, 0, stream>>>(wo, wob, 1179648);
  gemm_f32out<<<dim3(24, 32), 256, 0, stream>>>(att, wob, out, 3072, 3072);
}

// Round 3
// 510.028 us; speedup vs baseline: 2.3412x; 1.0507x over previous
//
#include <hip/hip_runtime.h>

typedef unsigned short u16;
typedef unsigned int u32;
typedef __attribute__((ext_vector_type(8))) __bf16 bf16x8;
typedef __attribute__((ext_vector_type(4))) float f32x4;
typedef __attribute__((ext_vector_type(4))) u32 u32x4;
typedef __attribute__((ext_vector_type(8))) u16 u16x8;
typedef __attribute__((ext_vector_type(4))) u16 u16x4;

#define S_LEN 2048
#define DM 3072
#define NH 24
#define NKV 8

__device__ __forceinline__ u16 f2b(float f) {
  u32 u = __builtin_bit_cast(u32, f);
  u = u + 0x7FFFu + ((u >> 16) & 1u);
  return (u16)(u >> 16);
}
__device__ __forceinline__ float b2f(u16 h) {
  u32 u = ((u32)h) << 16;
  return __builtin_bit_cast(float, u);
}
__device__ __forceinline__ f32x4 mfma16(bf16x8 a, bf16x8 b, f32x4 c) {
  return __builtin_amdgcn_mfma_f32_16x16x32_bf16(a, b, c, 0, 0, 0);
}
__device__ __forceinline__ void gload16(const u16* g, u16* l) {
  __builtin_amdgcn_global_load_lds((const __attribute__((address_space(1))) void*)g,
                                   (__attribute__((address_space(3))) void*)l, 16, 0, 0);
}

// ---------------- f32 -> bf16 conversion ----------------
__global__ __launch_bounds__(256) void cvt_kernel(const float* __restrict__ s,
                                                  u16* __restrict__ d, int n8) {
  int i = blockIdx.x * 256 + threadIdx.x;
  if (i >= n8) return;
  const f32x4* p = (const f32x4*)(s + (size_t)i * 8);
  f32x4 a = p[0], b = p[1];
  u16x8 o;
#pragma unroll
  for (int j = 0; j < 4; ++j) { o[j] = f2b(a[j]); o[j + 4] = f2b(b[j]); }
  *(u16x8*)(d + (size_t)i * 8) = o;
}

// ---------------- GEMM: C[m,n] = sum_k A[m,k] * B[n,k] ----------------
// 128x128 tile, BK=32, 4 waves (2x2 of 64x64), m97 structure.
// mode 0: bf16 row-major; mode 1: f32 row-major; mode 2: bf16 V^T
// (V^T layout: vT[(b*1024 + n)*2048 + s], where m = b*2048 + s).
__device__ __forceinline__ void gemm_body(const u16* __restrict__ A, const u16* __restrict__ B,
                                          void* __restrict__ Cv, int N, int K,
                                          int m0, int n0, int mode) {
  __shared__ __align__(16) u16 sA[128 * 32];
  __shared__ __align__(16) u16 sB[128 * 32];
  const int tid = threadIdx.x;
  const int w = tid >> 6, lane = tid & 63;
  const int l15 = lane & 15, g = lane >> 4;
  const int wr = w >> 1, wc = w & 1;
  f32x4 acc[4][4];
#pragma unroll
  for (int i = 0; i < 4; ++i)
#pragma unroll
    for (int j = 0; j < 4; ++j) acc[i][j] = 0.f;

  for (int k0 = 0; k0 < K; k0 += 32) {
    __syncthreads();
#pragma unroll
    for (int t = 0; t < 2; ++t) {
      int jb = w * 128 + t * 64;
      int jc = jb + lane;
      int row = jc >> 2, c8 = (jc & 3) << 3;
      gload16(A + (size_t)(m0 + row) * K + k0 + c8, sA + jb * 8);
      gload16(B + (size_t)(n0 + row) * K + k0 + c8, sB + jb * 8);
    }
    __syncthreads();
    bf16x8 af[4], bfr[4];
#pragma unroll
    for (int i = 0; i < 4; ++i) {
      af[i]  = *(const bf16x8*)(sA + (wr * 64 + i * 16 + l15) * 32 + g * 8);
      bfr[i] = *(const bf16x8*)(sB + (wc * 64 + i * 16 + l15) * 32 + g * 8);
    }
#pragma unroll
    for (int i = 0; i < 4; ++i)
#pragma unroll
      for (int j = 0; j < 4; ++j)
        acc[i][j] = mfma16(af[i], bfr[j], acc[i][j]);
  }
#pragma unroll
  for (int i = 0; i < 4; ++i)
#pragma unroll
    for (int j = 0; j < 4; ++j)
#pragma unroll
      for (int r = 0; r < 4; ++r) {
        int mm = m0 + wr * 64 + i * 16 + g * 4 + r;
        int nn = n0 + wc * 64 + j * 16 + l15;
        if (mode == 1)      ((float*)Cv)[(size_t)mm * N + nn] = acc[i][j][r];
        else if (mode == 0) ((u16*)Cv)[(size_t)mm * N + nn]   = f2b(acc[i][j][r]);
        else                ((u16*)Cv)[(size_t)nn * 2048 + (size_t)(mm >> 11) * 2097152 + (mm & 2047)]
                              = f2b(acc[i][j][r]);
      }
}

__global__ __launch_bounds__(256) void gemm_bf16out(const u16* __restrict__ A, const u16* __restrict__ B,
                                                    u16* __restrict__ C, int N, int K) {
  gemm_body(A, B, C, N, K, blockIdx.y * 128, blockIdx.x * 128, 0);
}
__global__ __launch_bounds__(256) void gemm_f32out(const u16* __restrict__ A, const u16* __restrict__ B,
                                                   float* __restrict__ C, int N, int K) {
  gemm_body(A, B, C, N, K, blockIdx.y * 128, blockIdx.x * 128, 1);
}
__global__ __launch_bounds__(256) void gemm_kv(const u16* __restrict__ A,
                                               const u16* __restrict__ Bk, const u16* __restrict__ Bv,
                                               u16* __restrict__ Ck, u16* __restrict__ Cv,
                                               int N, int K) {
  bool isv = blockIdx.x >= 8;
  gemm_body(A, isv ? Bv : Bk, isv ? Cv : Ck, N, K, blockIdx.y * 128, (blockIdx.x & 7) * 128,
            isv ? 2 : 0);
}

// ---------------- RoPE (in place, bf16) — used for K only ----------------
__global__ __launch_bounds__(256) void rope_kernel(u16* __restrict__ t, const float* __restrict__ fc,
                                                   const float* __restrict__ fs, int nheads, int total) {
  int idx = blockIdx.x * 256 + threadIdx.x;
  if (idx >= total) return;
  int c = idx & 7;
  int tmp = idx >> 3;
  int h = tmp % nheads;
  int row = tmp / nheads;
  int s = row & (S_LEN - 1);
  int d0 = c << 3;
  u16* base = t + (size_t)row * (nheads * 128) + h * 128;
  u16x8 lo = *(const u16x8*)(base + d0);
  u16x8 hi = *(const u16x8*)(base + 64 + d0);
  const float* cp = fc + s * 64 + d0;
  const float* sp = fs + s * 64 + d0;
  u16x8 olo, ohi;
#pragma unroll
  for (int j = 0; j < 8; ++j) {
    float cv = cp[j], sn = sp[j];
    float a = b2f(lo[j]), b = b2f(hi[j]);
    olo[j] = f2b(a * cv - b * sn);
    ohi[j] = f2b(b * cv + a * sn);
  }
  *(u16x8*)(base + d0) = olo;
  *(u16x8*)(base + 64 + d0) = ohi;
}

// ---------------- causal GQA flash attention ----------------
// grid: (S/128, H, B); block 512 (8 waves x 16 q-rows = 128 q/block).
// Swapped QK^T (lane owns q-row = lane&15), exp2-domain softmax with Q
// pre-scaled by 1/sqrt(128)*log2(e), RoPE(Q) fused at load. K and V^T
// double-buffered via global_load_lds w/ pre-swizzled sources. Defer-max.
__global__ __launch_bounds__(512) void attn_kernel(const u16* __restrict__ xq,
                                                   const u16* __restrict__ xk,
                                                   const u16* __restrict__ xvT,
                                                   const float* __restrict__ fc,
                                                   const float* __restrict__ fs,
                                                   u16* __restrict__ o) {
  __shared__ __align__(16) u16 smem[40960];     // 80 KB: K dbuf 32K, V^T dbuf 32K, P 16K
  const int tid = threadIdx.x;
  const int w = tid >> 6, lane = tid & 63;
  const int l15 = lane & 15, g = lane >> 4;
  u16* sP = smem + 32768 + w * 1024;            // per-wave P [16][64] bf16, XOR-swizzled
  const int b = blockIdx.z, h = blockIdx.y;
  const int qb = 15 - blockIdx.x;               // long blocks first
  const int kvh = h / 3;
  const int q0 = qb * 128;
  const int qrow = q0 + w * 16 + l15;
  const u16* qptr = xq + (size_t)(b * S_LEN + qrow) * DM + h * 128;
  const float sc2 = 0.08838834764831845f * 1.4426950408889634f;  // 1/sqrt(128)*log2e

  // load Q, apply RoPE + pre-scale in f32, repack to bf16 fragments
  bf16x8 qf[4];
#pragma unroll
  for (int dcp = 0; dcp < 2; ++dcp) {
    u16x8 Lo = *(const u16x8*)(qptr + dcp * 32 + g * 8);
    u16x8 Hi = *(const u16x8*)(qptr + 64 + dcp * 32 + g * 8);
    const float* cp = fc + qrow * 64 + dcp * 32 + g * 8;
    const float* sp = fs + qrow * 64 + dcp * 32 + g * 8;
    bf16x8 qlo, qhi;
#pragma unroll
    for (int j = 0; j < 8; ++j) {
      float cv = cp[j], sn = sp[j];
      float a = b2f(Lo[j]), bb = b2f(Hi[j]);
      qlo[j] = (__bf16)((a * cv - bb * sn) * sc2);
      qhi[j] = (__bf16)((bb * cv + a * sn) * sc2);
    }
    qf[dcp] = qlo;
    qf[dcp + 2] = qhi;
  }

  // staging addresses: dest linear chunk c holds global chunk c^(row&7) of its row
  const u16* ksrc = xk + (size_t)b * 2097152 + kvh * 128;          // [s][1024]
  const u16* vsrc = xvT + (size_t)(b * 1024 + kvh * 128) * 2048;   // [d][2048]
  int koff[2], vofs[2], dst[2];
#pragma unroll
  for (int r = 0; r < 2; ++r) {
    int ck = r * 512 + tid;                    // K tile: 64 rows x 16 chunks
    int krow = ck >> 4, kj = (ck & 15) ^ (krow & 7);
    koff[r] = krow * 1024 + kj * 8;
    int cv = r * 512 + tid;                    // V^T tile: 128 rows x 8 chunks
    int vrow = cv >> 3, vj = (cv & 7) ^ (vrow & 7);
    vofs[r] = vrow * 2048 + vj * 8;
    dst[r] = (r * 512 + (tid & 448)) * 8;      // wave-uniform LDS chunk base
  }

  u16 *sKc = smem, *sKn = smem + 8192;
  u16 *sVc = smem + 16384, *sVn = smem + 24576;

  f32x4 accO[8];
#pragma unroll
  for (int i = 0; i < 8; ++i) accO[i] = 0.f;
  float m = -1e30f, lsum = 0.f;
  const int nt = 2 * qb + 2;

#pragma unroll
  for (int r = 0; r < 2; ++r) gload16(ksrc + koff[r], sKc + dst[r]);
#pragma unroll
  for (int r = 0; r < 2; ++r) gload16(vsrc + vofs[r], sVc + dst[r]);
  __syncthreads();

  for (int t = 0; t < nt; ++t) {
    if (t + 1 < nt) {
      int k0n = (t + 1) * 64;
#pragma unroll
      for (int r = 0; r < 2; ++r) gload16(ksrc + (size_t)k0n * 1024 + koff[r], sKn + dst[r]);
#pragma unroll
      for (int r = 0; r < 2; ++r) gload16(vsrc + k0n + vofs[r], sVn + dst[r]);
    }
    // skip fully-masked waves (diagonal region): active iff some k <= some qrow
    if (64 * t <= q0 + w * 16 + 15) {
      // S^T[k][q] = sum_d K[k][d] Q[q][d]   (scores already in exp2 domain)
      f32x4 st[4];
      __builtin_amdgcn_s_setprio(1);
#pragma unroll
      for (int kt = 0; kt < 4; ++kt) {
        f32x4 a = 0.f;
        int row = kt * 16 + l15;
#pragma unroll
        for (int dc = 0; dc < 4; ++dc) {
          bf16x8 kf = *(const bf16x8*)(sKc + row * 128 + ((dc * 32 + g * 8) ^ ((row & 7) << 3)));
          a = mfma16(kf, qf[dc], a);
        }
        st[kt] = a;
      }
      __builtin_amdgcn_s_setprio(0);
      // causal mask (only needed on the last two tiles) + online softmax
      float sv[4][4];
      float pmax = -1e30f;
#pragma unroll
      for (int kt = 0; kt < 4; ++kt)
#pragma unroll
        for (int r = 0; r < 4; ++r) {
          float x = st[kt][r];
          if (t >= nt - 2) {
            int kk = t * 64 + kt * 16 + g * 4 + r;
            if (kk > qrow) x = -1e30f;
          }
          sv[kt][r] = x;
          pmax = fmaxf(pmax, x);
        }
      pmax = fmaxf(pmax, __shfl_xor(pmax, 16));
      pmax = fmaxf(pmax, __shfl_xor(pmax, 32));
      if (!__all(pmax - m <= 8.0f)) {          // defer-max: rescale only on real growth
        float mnew = fmaxf(m, pmax);
        float corr = exp2f(m - mnew);
        lsum *= corr;
#pragma unroll
        for (int i = 0; i < 8; ++i) accO[i] *= corr;
        m = mnew;
      }
      float ps = 0.f;
#pragma unroll
      for (int kt = 0; kt < 4; ++kt) {
        u16x4 pk;
#pragma unroll
        for (int r = 0; r < 4; ++r) {
          float p = exp2f(sv[kt][r] - m);
          ps += p;
          pk[r] = f2b(p);
        }
        *(u16x4*)(sP + ((l15 * 64 + kt * 16 + g * 4) ^ ((l15 & 7) << 3))) = pk;
      }
      ps += __shfl_xor(ps, 16);
      ps += __shfl_xor(ps, 32);
      lsum += ps;
      // PV: out^T[d][q] += V^T[d][k] * P[q][k]
      bf16x8 pf[2];
#pragma unroll
      for (int ck = 0; ck < 2; ++ck)
        pf[ck] = *(const bf16x8*)(sP + ((l15 * 64 + ck * 32 + g * 8) ^ ((l15 & 7) << 3)));
      __builtin_amdgcn_s_setprio(1);
#pragma unroll
      for (int dt = 0; dt < 8; ++dt) {
        int row = dt * 16 + l15;
#pragma unroll
        for (int ck = 0; ck < 2; ++ck) {
          bf16x8 vf = *(const bf16x8*)(sVc + row * 64 + ((ck * 32 + g * 8) ^ ((row & 7) << 3)));
          accO[dt] = mfma16(vf, pf[ck], accO[dt]);
        }
      }
      __builtin_amdgcn_s_setprio(0);
    }
    __syncthreads();                            // drains stage vmcnt + cur reads done
    u16* tk = sKc; sKc = sKn; sKn = tk;
    u16* tv = sVc; sVc = sVn; sVn = tv;
  }
  // epilogue: normalize, transpose via LDS, coalesced writes
  u16* sO = smem + w * 2048;                    // per-wave [16][128], XOR-swizzled
  float invl = 1.0f / lsum;
#pragma unroll
  for (int dt = 0; dt < 8; ++dt)
#pragma unroll
    for (int r = 0; r < 4; ++r) {
      int d = dt * 16 + g * 4 + r;
      sO[(l15 * 128 + d) ^ ((l15 & 7) << 3)] = f2b(accO[dt][r] * invl);
    }
#pragma unroll
  for (int p = 0; p < 4; ++p) {
    int idx = p * 64 + lane;
    int q = idx >> 4, d0 = (idx & 15) << 3;
    u32x4 v = *(const u32x4*)(sO + ((q * 128 + d0) ^ ((q & 7) << 3)));
    *(u32x4*)(o + (size_t)(b * S_LEN + q0 + w * 16 + q) * DM + h * 128 + d0) = v;
  }
}

// ---------------- launch ----------------
extern "C" void kernel_launch(void* const* d_in, const int* in_sizes, int n_in,
                              void* d_out, int out_size, void* d_ws, size_t ws_size,
                              hipStream_t stream) {
  const float* x  = (const float*)d_in[0];
  const float* fc = (const float*)d_in[1];
  const float* fs = (const float*)d_in[2];
  const float* wq = (const float*)d_in[4];
  const float* wk = (const float*)d_in[5];
  const float* wv = (const float*)d_in[6];
  const float* wo = (const float*)d_in[7];
  float* out = (float*)d_out;
  char* ws = (char*)d_ws;

  u16* xb  = (u16*)(ws);                 // x bf16      25,165,824
  u16* wqb = (u16*)(ws + 25165824);      // wq bf16     18,874,368
  u16* att = (u16*)(ws + 25165824);      // attn out (aliases wq/wk after death)
  u16* wkb = (u16*)(ws + 44040192);      // wk bf16      6,291,456
  u16* wvb = (u16*)(ws + 50331648);      // wv bf16      6,291,456
  u16* xqb = (u16*)(ws + 56623104);      // xq bf16     25,165,824
  u16* xkb = (u16*)(ws + 81788928);      // xk bf16      8,388,608
  u16* xvT = (u16*)(ws + 90177536);      // V^T bf16     8,388,608
  u16* wob = (u16*)(ws);                 // wo bf16 (aliases xb after death)

  cvt_kernel<<<6144, 256, 0, stream>>>(x,  xb,  1572864);
  cvt_kernel<<<4608, 256, 0, stream>>>(wq, wqb, 1179648);
  cvt_kernel<<<1536, 256, 0, stream>>>(wk, wkb,  393216);
  cvt_kernel<<<1536, 256, 0, stream>>>(wv, wvb,  393216);

  gemm_bf16out<<<dim3(24, 32), 256, 0, stream>>>(xb, wqb, xqb, 3072, 3072);
  gemm_kv<<<dim3(16, 32), 256, 0, stream>>>(xb, wkb, wvb, xkb, xvT, 1024, 3072);

  rope_kernel<<<1024, 256, 0, stream>>>(xkb, fc, fs, NKV, 4096 * NKV * 8);  // K only; Q-RoPE fused in attn

  attn_kernel<<<dim3(16, NH, 2), 512, 0, stream>>>(xqb, xkb, xvT, fc, fs, att);

  cvt_kernel<<<4608, 256, 0, stream>>>(wo, wob, 1179648);
  gemm_f32out<<<dim3(24, 32), 256, 0, stream>>>(att, wob, out, 3072, 3072);
}